// Round 14
// baseline (136.004 us; speedup 1.0000x reference)
//
#include <hip/hip_runtime.h>
#include <stdint.h>
#include <stddef.h>

#define DIM 1024
#define NEXP 8
#define HID 512
#define NTOK 16384  // 4 * 4096
#define NB_HIST 64
#define NB_ROUTER 1024  // router blocks (16 tokens each)
#define NB_CAST 512     // weight-cast blocks appended after router blocks

typedef __attribute__((ext_vector_type(4))) float f32x4;
typedef __attribute__((ext_vector_type(8))) short short8;
typedef __attribute__((ext_vector_type(2))) unsigned int u32x2;
typedef __attribute__((ext_vector_type(4))) unsigned int u32x4;

__device__ __forceinline__ unsigned short f2b(float f) {
  unsigned int u = __float_as_uint(f);
  return (unsigned short)((u + 0x7FFFu + ((u >> 16) & 1u)) >> 16);  // RNE
}

// packed fp32x2 -> bf16x2 in one VALU op (RNE); round-11 win.
__device__ __forceinline__ unsigned int pk_bf16(float a, float b) {
  unsigned int r;
  asm volatile("v_cvt_pk_bf16_f32 %0, %1, %2" : "=v"(r) : "v"(a), "v"(b));
  return r;
}

__device__ __forceinline__ void gload_lds16(const void* g, void* l) {
  __builtin_amdgcn_global_load_lds((const __attribute__((address_space(1))) void*)g,
                                   (__attribute__((address_space(3))) void*)l, 16, 0, 0);
}

// Router (pure read) + both weight casts (round-12 layout — round-13 showed
// moving cast work between kernels is zero-sum; restored).
__global__ __launch_bounds__(256) void k_router_cast(
    const float* __restrict__ x, const float* __restrict__ wr,
    int* __restrict__ eid,
    const float* __restrict__ wfc, const float* __restrict__ wpj,
    unsigned short* __restrict__ oa, unsigned short* __restrict__ ob) {
  int bid = blockIdx.x;
  if (bid < NB_ROUTER) {
    int w = threadIdx.x >> 6, lane = threadIdx.x & 63;
    int t0 = bid * 16 + w * 4;
    const float* xr = x + (size_t)t0 * DIM;
    float s[4][NEXP];
#pragma unroll
    for (int j = 0; j < 4; j++)
#pragma unroll
      for (int e = 0; e < NEXP; e++) s[j][e] = 0.f;
#pragma unroll
    for (int i = 0; i < 4; i++) {
      f32x4 xv[4];
#pragma unroll
      for (int j = 0; j < 4; j++) xv[j] = *(const f32x4*)(xr + j * DIM + lane * 4 + 256 * i);
#pragma unroll
      for (int e = 0; e < NEXP; e++) {
        f32x4 wv = *(const f32x4*)(wr + e * DIM + lane * 4 + 256 * i);
#pragma unroll
        for (int j = 0; j < 4; j++)
          s[j][e] += xv[j].x * wv.x + xv[j].y * wv.y + xv[j].z * wv.z + xv[j].w * wv.w;
      }
    }
#pragma unroll
    for (int j = 0; j < 4; j++)
#pragma unroll
      for (int e = 0; e < NEXP; e++) {
        float v = s[j][e];
#pragma unroll
        for (int off = 32; off > 0; off >>= 1) v += __shfl_xor(v, off);
        s[j][e] = v;
      }
    if (lane == 0) {
#pragma unroll
      for (int j = 0; j < 4; j++) {
        int be = 0;
        float bv = s[j][0];
#pragma unroll
        for (int e = 1; e < NEXP; e++) {
          if (s[j][e] > bv) { bv = s[j][e]; be = e; }
        }
        eid[t0 + j] = be;
      }
    }
  } else {
    const int n4 = NEXP * HID * DIM / 4;
    int stride = NB_CAST * 256;
    for (int i = (bid - NB_ROUTER) * 256 + (int)threadIdx.x; i < n4; i += stride) {
      f32x4 va = ((const f32x4*)wfc)[i];
      f32x4 vb = ((const f32x4*)wpj)[i];
      u32x2 ua, ub;
      ua.x = pk_bf16(va.x, va.y); ua.y = pk_bf16(va.z, va.w);
      ub.x = pk_bf16(vb.x, vb.y); ub.y = pk_bf16(vb.z, vb.w);
      ((u32x2*)oa)[i] = ua;
      ((u32x2*)ob)[i] = ub;
    }
  }
}

__global__ __launch_bounds__(256) void k_hist(const int* __restrict__ eid,
                                              int* __restrict__ bc) {
  __shared__ int h[NEXP];
  if (threadIdx.x < NEXP) h[threadIdx.x] = 0;
  __syncthreads();
  int tok = blockIdx.x * (NTOK / NB_HIST) + threadIdx.x;
  atomicAdd(&h[eid[tok]], 1);
  __syncthreads();
  if (threadIdx.x < NEXP) bc[blockIdx.x * NEXP + threadIdx.x] = h[threadIdx.x];
}

__global__ void k_scan(const int* __restrict__ bc, int* __restrict__ offs,
                       int* __restrict__ base) {
  __shared__ int cnt[NEXP];
  __shared__ int so[NEXP + 1];
  int t = threadIdx.x;
  if (t < NEXP) {
    int run = 0;
    for (int b = 0; b < NB_HIST; b++) {
      base[b * NEXP + t] = run;
      run += bc[b * NEXP + t];
    }
    cnt[t] = run;
  }
  __syncthreads();
  if (t == 0) {
    int a = 0;
    for (int e = 0; e < NEXP; e++) { so[e] = a; a += cnt[e]; }
    so[NEXP] = a;
  }
  __syncthreads();
  if (t < NEXP + 1) offs[t] = so[t];
  for (int i = t; i < NB_HIST * NEXP; i += blockDim.x) base[i] += so[i % NEXP];
}

__global__ __launch_bounds__(256) void k_scatter(const int* __restrict__ eid,
                                                 const int* __restrict__ base,
                                                 int* __restrict__ tlist) {
  __shared__ int cur[NEXP];
  if (threadIdx.x < NEXP) cur[threadIdx.x] = base[blockIdx.x * NEXP + threadIdx.x];
  __syncthreads();
  int tok = blockIdx.x * (NTOK / NB_HIST) + threadIdx.x;
  int e = eid[tok];
  int pos = atomicAdd(&cur[e], 1);
  tlist[pos] = tok;
}

// XCD-chunked mapping over G tiles (G % 8 == 0), (expert, m-block, n-block), n fastest.
__device__ __forceinline__ bool tile_map_g(const int* offs, int NB, int bid, int G,
                                           int& e, int& mb, int& nb) {
  int l = (bid & 7) * (G >> 3) + (bid >> 3);
  e = -1; mb = 0; nb = 0;
  int acc2 = 0;
#pragma unroll
  for (int i = 0; i < NEXP; i++) {
    int mi = offs[i + 1] - offs[i];
    int tb = ((mi + 127) >> 7) * NB;
    if (e < 0 && l < acc2 + tb) {
      int r = l - acc2;
      e = i; mb = r / NB; nb = r % NB;
    }
    acc2 += tb;
  }
  return e >= 0;
}

// fc GEMM — round-14: A staged as RAW FP32 via global_load_lds (pj's proven
// ring-3 depth-2 schedule, 6 loads/STAGE, steady vmcnt(6), one barrier/step);
// fp32->bf16 conversion moved to the READ side (2x ds_read_b128 + 4 cvt_pk per
// fragment). Removes the reg-roundtrip A path whose per-step vmcnt stall made
// fc 10us slower than pj at identical total K-step count.
// A-swizzle (128B rows, 8x16B chunks): slot s of row r holds global chunk
// s^(r&7); read spread = 2 lanes/slot (free). B unchanged from r12.
__global__ __launch_bounds__(256) void k_gemm_fc(
    const float* __restrict__ x, const unsigned short* __restrict__ wb,
    const int* __restrict__ offs, const int* __restrict__ tlist,
    unsigned short* __restrict__ hout) {
  constexpr int KDIM = DIM, NDIM = HID;
  int e, mb, nb;
  if (!tile_map_g(offs, 4, (int)blockIdx.x, (int)gridDim.x, e, mb, nb)) return;
  int off = offs[e], me = offs[e + 1] - off, m0 = mb * 128, n0 = nb * 128;

  __shared__ float Af[3][128 * 32];           // 48 KB (fp32 A tiles)
  __shared__ unsigned short Bs[3][128 * 32];  // 24 KB

  int t = threadIdx.x, lane = t & 63, w = t >> 6;
  int wm = w >> 1, wn = w & 1;

  // A staging: issue i covers rows i*32 + w*8 + (lane>>3); lane's 16B slot is
  // (lane&7), which must hold global chunk (lane&7)^((lane>>3)&7).
  int cha = ((lane & 7) ^ ((lane >> 3) & 7)) * 4;  // fp32 offset
  // B staging (r12): slot lane&3 of row w*16+(lane>>2) holds chunk ^((r>>1)&3)
  int kb = (lane & 3) ^ ((lane >> 3) & 3);

  const float* asrcf[4];
#pragma unroll
  for (int i = 0; i < 4; i++) {
    int r = i * 32 + w * 8 + (lane >> 3);
    int gm = m0 + r;
    if (gm > me - 1) gm = me - 1;  // clamp pad rows (masked at epilogue)
    asrcf[i] = x + (size_t)tlist[off + gm] * DIM + cha;
  }
  const unsigned short* bsrc[2];
#pragma unroll
  for (int i = 0; i < 2; i++) {
    int r = i * 64 + w * 16 + (lane >> 2);
    bsrc[i] = wb + ((size_t)e * NDIM + n0 + r) * (size_t)KDIM + kb * 8;
  }

  f32x4 acc[4][4] = {};
  constexpr int NT = KDIM / 32;  // 32

  float* a0 = &Af[0][0]; unsigned short* b0 = &Bs[0][0];
  float* a1 = &Af[1][0]; unsigned short* b1 = &Bs[1][0];
  float* a2 = &Af[2][0]; unsigned short* b2 = &Bs[2][0];

#define STAGE(kt_, da_, db_)                                           \
  do {                                                                 \
    gload_lds16(asrcf[0] + (kt_) * 32, (da_) + (0 * 32 + w * 8) * 32); \
    gload_lds16(asrcf[1] + (kt_) * 32, (da_) + (1 * 32 + w * 8) * 32); \
    gload_lds16(asrcf[2] + (kt_) * 32, (da_) + (2 * 32 + w * 8) * 32); \
    gload_lds16(asrcf[3] + (kt_) * 32, (da_) + (3 * 32 + w * 8) * 32); \
    gload_lds16(bsrc[0] + (kt_) * 32, (db_) + (w * 16) * 32);          \
    gload_lds16(bsrc[1] + (kt_) * 32, (db_) + (64 + w * 16) * 32);     \
  } while (0)

  STAGE(0, a0, b0);
  STAGE(1, a1, b1);

  for (int kt = 0; kt < NT; kt++) {
    if (kt < NT - 1) {
      asm volatile("s_waitcnt vmcnt(6)" ::: "memory");
    } else {
      asm volatile("s_waitcnt vmcnt(0)" ::: "memory");
    }
    __builtin_amdgcn_s_barrier();

    if (kt + 2 < NT) STAGE(kt + 2, a2, b2);

    short8 af[4], bf[4];
#pragma unroll
    for (int i = 0; i < 4; i++) {
      int ra = wm * 64 + i * 16 + (lane & 15);
      int c = lane >> 4;
      int s0 = (2 * c) ^ (ra & 7), s1 = (2 * c + 1) ^ (ra & 7);
      f32x4 lo = *(const f32x4*)&a0[ra * 32 + s0 * 4];
      f32x4 hi = *(const f32x4*)&a0[ra * 32 + s1 * 4];
      u32x4 pkv;
      pkv.x = pk_bf16(lo.x, lo.y); pkv.y = pk_bf16(lo.z, lo.w);
      pkv.z = pk_bf16(hi.x, hi.y); pkv.w = pk_bf16(hi.z, hi.w);
      af[i] = *(short8*)&pkv;
      int rbb = wn * 64 + i * 16 + (lane & 15);
      int cb = (lane >> 4) ^ ((rbb >> 1) & 3);
      bf[i] = *(const short8*)&b0[rbb * 32 + cb * 8];
    }
    __builtin_amdgcn_s_setprio(1);
#pragma unroll
    for (int mi = 0; mi < 4; mi++)
#pragma unroll
      for (int ni = 0; ni < 4; ni++)
        acc[mi][ni] =
            __builtin_amdgcn_mfma_f32_16x16x32_bf16(af[mi], bf[ni], acc[mi][ni], 0, 0, 0);
    __builtin_amdgcn_s_setprio(0);

    float* ta = a0; a0 = a1; a1 = a2; a2 = ta;
    unsigned short* tb = b0; b0 = b1; b1 = b2; b2 = tb;
  }
#undef STAGE

  int rb = (lane >> 4) * 4, cb = lane & 15;
#pragma unroll
  for (int mi = 0; mi < 4; mi++) {
#pragma unroll
    for (int j = 0; j < 4; j++) {
      int ml = wm * 64 + mi * 16 + rb + j;
      if (m0 + ml < me) {
#pragma unroll
        for (int ni = 0; ni < 4; ni++) {
          int col = n0 + wn * 64 + ni * 16 + cb;
          float v = acc[mi][ni][j];
          v = (v >= 0.f) ? v * v : 0.25f * v * v;  // leaky(0.5) then square
          hout[(size_t)(off + m0 + ml) * HID + col] = f2b(v);
        }
      }
    }
  }
}

// proj GEMM — round-9/12 measured-best (128x128, ring-3 48KB, depth-2, vmcnt(4)).
__global__ __launch_bounds__(256) void k_gemm_pj(
    const unsigned short* __restrict__ hin, const unsigned short* __restrict__ wb,
    const int* __restrict__ offs, const int* __restrict__ tlist,
    float* __restrict__ out) {
  constexpr int KDIM = HID, NDIM = DIM;
  int e, mb, nb;
  if (!tile_map_g(offs, 8, (int)blockIdx.x, (int)gridDim.x, e, mb, nb)) return;
  int off = offs[e], me = offs[e + 1] - off, m0 = mb * 128, n0 = nb * 128;

  __shared__ unsigned short lds[3][2][128 * 32];

  int t = threadIdx.x, lane = t & 63, w = t >> 6;
  int wm = w >> 1, wn = w & 1;

  int kb = (lane & 3) ^ ((lane >> 3) & 3);

  const unsigned short* asrc[2];
  const unsigned short* bsrc[2];
#pragma unroll
  for (int i = 0; i < 2; i++) {
    int r = i * 64 + w * 16 + (lane >> 2);
    int gm = m0 + r;
    if (gm > me - 1) gm = me - 1;
    asrc[i] = hin + (size_t)(off + gm) * KDIM + kb * 8;
    bsrc[i] = wb + ((size_t)e * NDIM + n0 + r) * (size_t)KDIM + kb * 8;
  }

  f32x4 acc[4][4] = {};
  constexpr int NT = KDIM / 32;  // 16

  unsigned short* b0a = &lds[0][0][0]; unsigned short* b0b = &lds[0][1][0];
  unsigned short* b1a = &lds[1][0][0]; unsigned short* b1b = &lds[1][1][0];
  unsigned short* b2a = &lds[2][0][0]; unsigned short* b2b = &lds[2][1][0];

#define STAGE(kt_, da_, db_)                                       \
  do {                                                             \
    gload_lds16(asrc[0] + (kt_) * 32, (da_) + (w * 16) * 32);      \
    gload_lds16(asrc[1] + (kt_) * 32, (da_) + (64 + w * 16) * 32); \
    gload_lds16(bsrc[0] + (kt_) * 32, (db_) + (w * 16) * 32);      \
    gload_lds16(bsrc[1] + (kt_) * 32, (db_) + (64 + w * 16) * 32); \
  } while (0)

  STAGE(0, b0a, b0b);
  STAGE(1, b1a, b1b);

  for (int kt = 0; kt < NT; kt++) {
    if (kt < NT - 1) {
      asm volatile("s_waitcnt vmcnt(4)" ::: "memory");
    } else {
      asm volatile("s_waitcnt vmcnt(0)" ::: "memory");
    }
    __builtin_amdgcn_s_barrier();

    if (kt + 2 < NT) STAGE(kt + 2, b2a, b2b);

    short8 af[4], bf[4];
#pragma unroll
    for (int i = 0; i < 4; i++) {
      int ra = wm * 64 + i * 16 + (lane & 15);
      int ca = (lane >> 4) ^ ((ra >> 1) & 3);
      af[i] = *(const short8*)&b0a[ra * 32 + ca * 8];
      int rbb = wn * 64 + i * 16 + (lane & 15);
      int cb = (lane >> 4) ^ ((rbb >> 1) & 3);
      bf[i] = *(const short8*)&b0b[rbb * 32 + cb * 8];
    }
    __builtin_amdgcn_s_setprio(1);
#pragma unroll
    for (int mi = 0; mi < 4; mi++)
#pragma unroll
      for (int ni = 0; ni < 4; ni++)
        acc[mi][ni] =
            __builtin_amdgcn_mfma_f32_16x16x32_bf16(af[mi], bf[ni], acc[mi][ni], 0, 0, 0);
    __builtin_amdgcn_s_setprio(0);

    unsigned short* ta = b0a; b0a = b1a; b1a = b2a; b2a = ta;
    unsigned short* tb = b0b; b0b = b1b; b1b = b2b; b2b = tb;
  }
#undef STAGE

  int rb = (lane >> 4) * 4, cb = lane & 15;
#pragma unroll
  for (int mi = 0; mi < 4; mi++) {
#pragma unroll
    for (int j = 0; j < 4; j++) {
      int ml = wm * 64 + mi * 16 + rb + j;
      if (m0 + ml < me) {
        int tok = tlist[off + m0 + ml];
#pragma unroll
        for (int ni = 0; ni < 4; ni++) {
          int col = n0 + wn * 64 + ni * 16 + cb;
          out[(size_t)tok * DIM + col] = acc[mi][ni][j];
        }
      }
    }
  }
}

extern "C" void kernel_launch(void* const* d_in, const int* in_sizes, int n_in,
                              void* d_out, int out_size, void* d_ws, size_t ws_size,
                              hipStream_t stream) {
  const float* x = (const float*)d_in[0];
  const float* wr = (const float*)d_in[1];
  const float* wfc = (const float*)d_in[2];
  const float* wpj = (const float*)d_in[3];
  float* out = (float*)d_out;

  uintptr_t p = (uintptr_t)d_ws;
  int* offs = (int*)p;  p += 256;
  int* bc = (int*)p;    p += sizeof(int) * NB_HIST * NEXP;
  int* base = (int*)p;  p += sizeof(int) * NB_HIST * NEXP;
  int* eid = (int*)p;   p += sizeof(int) * NTOK;
  int* tlist = (int*)p; p += sizeof(int) * NTOK;
  unsigned short* wfc_b = (unsigned short*)p; p += (size_t)NEXP * HID * DIM * 2;
  unsigned short* wpj_b = (unsigned short*)p; p += (size_t)NEXP * DIM * HID * 2;
  unsigned short* hbuf = (unsigned short*)p;  p += (size_t)NTOK * HID * 2;

  k_router_cast<<<NB_ROUTER + NB_CAST, 256, 0, stream>>>(
      x, wr, eid, wfc, wpj, wfc_b, wpj_b);
  k_hist<<<NB_HIST, 256, 0, stream>>>(eid, bc);
  k_scan<<<1, 256, 0, stream>>>(bc, offs, base);
  k_scatter<<<NB_HIST, 256, 0, stream>>>(eid, base, tlist);
  // fc: 540 tiles max -> grid 544 (div by 8)
  k_gemm_fc<<<dim3(544), 256, 0, stream>>>(x, wfc_b, offs, tlist, hbuf);
  // proj: 128x128 tiles -> 1080 max (div by 8)
  k_gemm_pj<<<dim3(1080), 256, 0, stream>>>(hbuf, wpj_b, offs, tlist, out);
}

// Round 15
// 112.271 us; speedup vs baseline: 1.2114x; 1.2114x over previous
//
#include <hip/hip_runtime.h>
#include <stdint.h>
#include <stddef.h>

#define DIM 1024
#define NEXP 8
#define HID 512
#define NTOK 16384  // 4 * 4096
#define NB_HIST 64
#define NB_ROUTER 1024  // router blocks (16 tokens each)
#define NB_CAST 512     // weight-cast blocks appended after router blocks

typedef __attribute__((ext_vector_type(4))) float f32x4;
typedef __attribute__((ext_vector_type(8))) short short8;
typedef __attribute__((ext_vector_type(2))) unsigned int u32x2;
typedef __attribute__((ext_vector_type(4))) unsigned int u32x4;

__device__ __forceinline__ unsigned short f2b(float f) {
  unsigned int u = __float_as_uint(f);
  return (unsigned short)((u + 0x7FFFu + ((u >> 16) & 1u)) >> 16);  // RNE
}

// packed fp32x2 -> bf16x2 in one VALU op (RNE); round-11 win.
__device__ __forceinline__ unsigned int pk_bf16(float a, float b) {
  unsigned int r;
  asm volatile("v_cvt_pk_bf16_f32 %0, %1, %2" : "=v"(r) : "v"(a), "v"(b));
  return r;
}

__device__ __forceinline__ void gload_lds16(const void* g, void* l) {
  __builtin_amdgcn_global_load_lds((const __attribute__((address_space(1))) void*)g,
                                   (__attribute__((address_space(3))) void*)l, 16, 0, 0);
}

// Router (pure read) + both weight casts (round-12 layout).
__global__ __launch_bounds__(256) void k_router_cast(
    const float* __restrict__ x, const float* __restrict__ wr,
    int* __restrict__ eid,
    const float* __restrict__ wfc, const float* __restrict__ wpj,
    unsigned short* __restrict__ oa, unsigned short* __restrict__ ob) {
  int bid = blockIdx.x;
  if (bid < NB_ROUTER) {
    int w = threadIdx.x >> 6, lane = threadIdx.x & 63;
    int t0 = bid * 16 + w * 4;
    const float* xr = x + (size_t)t0 * DIM;
    float s[4][NEXP];
#pragma unroll
    for (int j = 0; j < 4; j++)
#pragma unroll
      for (int e = 0; e < NEXP; e++) s[j][e] = 0.f;
#pragma unroll
    for (int i = 0; i < 4; i++) {
      f32x4 xv[4];
#pragma unroll
      for (int j = 0; j < 4; j++) xv[j] = *(const f32x4*)(xr + j * DIM + lane * 4 + 256 * i);
#pragma unroll
      for (int e = 0; e < NEXP; e++) {
        f32x4 wv = *(const f32x4*)(wr + e * DIM + lane * 4 + 256 * i);
#pragma unroll
        for (int j = 0; j < 4; j++)
          s[j][e] += xv[j].x * wv.x + xv[j].y * wv.y + xv[j].z * wv.z + xv[j].w * wv.w;
      }
    }
#pragma unroll
    for (int j = 0; j < 4; j++)
#pragma unroll
      for (int e = 0; e < NEXP; e++) {
        float v = s[j][e];
#pragma unroll
        for (int off = 32; off > 0; off >>= 1) v += __shfl_xor(v, off);
        s[j][e] = v;
      }
    if (lane == 0) {
#pragma unroll
      for (int j = 0; j < 4; j++) {
        int be = 0;
        float bv = s[j][0];
#pragma unroll
        for (int e = 1; e < NEXP; e++) {
          if (s[j][e] > bv) { bv = s[j][e]; be = e; }
        }
        eid[t0 + j] = be;
      }
    }
  } else {
    const int n4 = NEXP * HID * DIM / 4;
    int stride = NB_CAST * 256;
    for (int i = (bid - NB_ROUTER) * 256 + (int)threadIdx.x; i < n4; i += stride) {
      f32x4 va = ((const f32x4*)wfc)[i];
      f32x4 vb = ((const f32x4*)wpj)[i];
      u32x2 ua, ub;
      ua.x = pk_bf16(va.x, va.y); ua.y = pk_bf16(va.z, va.w);
      ub.x = pk_bf16(vb.x, vb.y); ub.y = pk_bf16(vb.z, vb.w);
      ((u32x2*)oa)[i] = ua;
      ((u32x2*)ob)[i] = ub;
    }
  }
}

__global__ __launch_bounds__(256) void k_hist(const int* __restrict__ eid,
                                              int* __restrict__ bc) {
  __shared__ int h[NEXP];
  if (threadIdx.x < NEXP) h[threadIdx.x] = 0;
  __syncthreads();
  int tok = blockIdx.x * (NTOK / NB_HIST) + threadIdx.x;
  atomicAdd(&h[eid[tok]], 1);
  __syncthreads();
  if (threadIdx.x < NEXP) bc[blockIdx.x * NEXP + threadIdx.x] = h[threadIdx.x];
}

__global__ void k_scan(const int* __restrict__ bc, int* __restrict__ offs,
                       int* __restrict__ base) {
  __shared__ int cnt[NEXP];
  __shared__ int so[NEXP + 1];
  int t = threadIdx.x;
  if (t < NEXP) {
    int run = 0;
    for (int b = 0; b < NB_HIST; b++) {
      base[b * NEXP + t] = run;
      run += bc[b * NEXP + t];
    }
    cnt[t] = run;
  }
  __syncthreads();
  if (t == 0) {
    int a = 0;
    for (int e = 0; e < NEXP; e++) { so[e] = a; a += cnt[e]; }
    so[NEXP] = a;
  }
  __syncthreads();
  if (t < NEXP + 1) offs[t] = so[t];
  for (int i = t; i < NB_HIST * NEXP; i += blockDim.x) base[i] += so[i % NEXP];
}

__global__ __launch_bounds__(256) void k_scatter(const int* __restrict__ eid,
                                                 const int* __restrict__ base,
                                                 int* __restrict__ tlist) {
  __shared__ int cur[NEXP];
  if (threadIdx.x < NEXP) cur[threadIdx.x] = base[blockIdx.x * NEXP + threadIdx.x];
  __syncthreads();
  int tok = blockIdx.x * (NTOK / NB_HIST) + threadIdx.x;
  int e = eid[tok];
  int pos = atomicAdd(&cur[e], 1);
  tlist[pos] = tok;
}

// XCD-chunked mapping over G tiles (G % 8 == 0), (expert, m-block, n-block), n fastest.
__device__ __forceinline__ bool tile_map_g(const int* offs, int NB, int bid, int G,
                                           int& e, int& mb, int& nb) {
  int l = (bid & 7) * (G >> 3) + (bid >> 3);
  e = -1; mb = 0; nb = 0;
  int acc2 = 0;
#pragma unroll
  for (int i = 0; i < NEXP; i++) {
    int mi = offs[i + 1] - offs[i];
    int tb = ((mi + 127) >> 7) * NB;
    if (e < 0 && l < acc2 + tb) {
      int r = l - acc2;
      e = i; mb = r / NB; nb = r % NB;
    }
    acc2 += tb;
  }
  return e >= 0;
}

// fc GEMM — round-12 structure with ONE surgical delta: A registers depth-2.
// Two static reg sets (p/q via unroll-by-2); A(kt+2) issued in iter kt, so the
// per-step wait consumes loads issued ~2 MFMA-phases (~600cyc) ago instead of 1.
// FIFO ledger: per-iter issue [A x4, B x2]; prologue A0,B0,A1,B1; steady
// outstanding at loop top = 12, need oldest 6 -> steady vmcnt(6); tail vmcnt(0).
// Everything else (B ring-3 depth-2, write->lgkm->barrier->read order, pins,
// 48KB LDS, swizzles) byte-identical to r12's measured-best fc.
__global__ __launch_bounds__(256) void k_gemm_fc(
    const float* __restrict__ x, const unsigned short* __restrict__ wb,
    const int* __restrict__ offs, const int* __restrict__ tlist,
    unsigned short* __restrict__ hout) {
  constexpr int KDIM = DIM, NDIM = HID;
  int e, mb, nb;
  if (!tile_map_g(offs, 4, (int)blockIdx.x, (int)gridDim.x, e, mb, nb)) return;
  int off = offs[e], me = offs[e + 1] - off, m0 = mb * 128, n0 = nb * 128;

  __shared__ unsigned short As[3][128 * 32];
  __shared__ unsigned short Bs[3][128 * 32];

  int t = threadIdx.x, lane = t & 63, w = t >> 6;
  int wm = w >> 1, wn = w & 1;

  int kb = (lane & 3) ^ ((lane >> 3) & 3);

  const unsigned short* bsrc[2];
  const float* af32[2];
#pragma unroll
  for (int i = 0; i < 2; i++) {
    int r = i * 64 + w * 16 + (lane >> 2);
    bsrc[i] = wb + ((size_t)e * NDIM + n0 + r) * (size_t)KDIM + kb * 8;
    int gm = m0 + r;
    if (gm > me - 1) gm = me - 1;
    af32[i] = x + (size_t)tlist[off + gm] * DIM + kb * 8;
  }
  int awoff0 = (w * 16) * 32 + lane * 8;
  int awoff1 = (64 + w * 16) * 32 + lane * 8;

  f32x4 acc[4][4] = {};
  constexpr int NT = KDIM / 32;  // 32, even

  unsigned short* a0 = &As[0][0]; unsigned short* b0 = &Bs[0][0];
  unsigned short* a1 = &As[1][0]; unsigned short* b1 = &Bs[1][0];
  unsigned short* a2 = &As[2][0]; unsigned short* b2 = &Bs[2][0];

  f32x4 p0, p1, p2, p3;  // A regs, even kt
  f32x4 q0, q1, q2, q3;  // A regs, odd kt

#define ISSUE_A(kt_, R0, R1, R2, R3)                  \
  do {                                                \
    R0 = *(const f32x4*)(af32[0] + (kt_) * 32);       \
    R1 = *(const f32x4*)(af32[0] + (kt_) * 32 + 4);   \
    R2 = *(const f32x4*)(af32[1] + (kt_) * 32);       \
    R3 = *(const f32x4*)(af32[1] + (kt_) * 32 + 4);   \
  } while (0)
#define ISSUE_B(kt_, db_)                                         \
  do {                                                            \
    gload_lds16(bsrc[0] + (kt_) * 32, (db_) + (w * 16) * 32);     \
    gload_lds16(bsrc[1] + (kt_) * 32, (db_) + (64 + w * 16) * 32);\
  } while (0)
#define WRITE_A(da_, R0, R1, R2, R3)                              \
  do {                                                            \
    u32x4 c0, c1;                                                 \
    c0.x = pk_bf16(R0.x, R0.y); c0.y = pk_bf16(R0.z, R0.w);       \
    c0.z = pk_bf16(R1.x, R1.y); c0.w = pk_bf16(R1.z, R1.w);       \
    c1.x = pk_bf16(R2.x, R2.y); c1.y = pk_bf16(R2.z, R2.w);       \
    c1.z = pk_bf16(R3.x, R3.y); c1.w = pk_bf16(R3.z, R3.w);       \
    *(u32x4*)&(da_)[awoff0] = c0;                                 \
    *(u32x4*)&(da_)[awoff1] = c1;                                 \
  } while (0)

// One K-step: W* holds A(kt) (written to LDS now, then refilled with A(kt+2)).
#define FC_BODY(kt_, W0, W1, W2, W3)                                            \
  do {                                                                          \
    if ((kt_) < NT - 1) {                                                       \
      asm volatile("s_waitcnt vmcnt(6)" ::: "memory");                          \
    } else {                                                                    \
      asm volatile("s_waitcnt vmcnt(0)" ::: "memory");                          \
    }                                                                           \
    __builtin_amdgcn_sched_barrier(0);                                          \
    WRITE_A(a0, W0, W1, W2, W3);                                                \
    asm volatile("s_waitcnt lgkmcnt(0)" ::: "memory");                          \
    __builtin_amdgcn_sched_barrier(0);                                          \
    __builtin_amdgcn_s_barrier();                                               \
    if ((kt_) + 2 < NT) {                                                       \
      ISSUE_A((kt_) + 2, W0, W1, W2, W3);                                       \
      ISSUE_B((kt_) + 2, b2);                                                   \
    }                                                                           \
    short8 af[4], bf[4];                                                        \
    _Pragma("unroll") for (int i = 0; i < 4; i++) {                             \
      int ra = wm * 64 + i * 16 + (lane & 15);                                  \
      int ca = (lane >> 4) ^ ((ra >> 1) & 3);                                   \
      af[i] = *(const short8*)&a0[ra * 32 + ca * 8];                            \
      int rbb = wn * 64 + i * 16 + (lane & 15);                                 \
      int cb2 = (lane >> 4) ^ ((rbb >> 1) & 3);                                 \
      bf[i] = *(const short8*)&b0[rbb * 32 + cb2 * 8];                          \
    }                                                                           \
    __builtin_amdgcn_s_setprio(1);                                              \
    _Pragma("unroll") for (int mi = 0; mi < 4; mi++)                            \
      _Pragma("unroll") for (int ni = 0; ni < 4; ni++)                          \
        acc[mi][ni] = __builtin_amdgcn_mfma_f32_16x16x32_bf16(                  \
            af[mi], bf[ni], acc[mi][ni], 0, 0, 0);                              \
    __builtin_amdgcn_s_setprio(0);                                              \
    unsigned short* ta_ = a0; a0 = a1; a1 = a2; a2 = ta_;                       \
    unsigned short* tb_ = b0; b0 = b1; b1 = b2; b2 = tb_;                       \
  } while (0)

  // prologue: A(0)->p, B(0), A(1)->q, B(1)  (12 outstanding)
  ISSUE_A(0, p0, p1, p2, p3);
  ISSUE_B(0, b0);
  ISSUE_A(1, q0, q1, q2, q3);
  ISSUE_B(1, b1);

  for (int kt = 0; kt < NT; kt += 2) {
    FC_BODY(kt, p0, p1, p2, p3);
    FC_BODY(kt + 1, q0, q1, q2, q3);
  }
#undef ISSUE_A
#undef ISSUE_B
#undef WRITE_A
#undef FC_BODY

  int rb = (lane >> 4) * 4, cb = lane & 15;
#pragma unroll
  for (int mi = 0; mi < 4; mi++) {
#pragma unroll
    for (int j = 0; j < 4; j++) {
      int ml = wm * 64 + mi * 16 + rb + j;
      if (m0 + ml < me) {
#pragma unroll
        for (int ni = 0; ni < 4; ni++) {
          int col = n0 + wn * 64 + ni * 16 + cb;
          float v = acc[mi][ni][j];
          v = (v >= 0.f) ? v * v : 0.25f * v * v;  // leaky(0.5) then square
          hout[(size_t)(off + m0 + ml) * HID + col] = f2b(v);
        }
      }
    }
  }
}

// proj GEMM — round-9/12 measured-best (128x128, ring-3 48KB, depth-2, vmcnt(4)).
__global__ __launch_bounds__(256) void k_gemm_pj(
    const unsigned short* __restrict__ hin, const unsigned short* __restrict__ wb,
    const int* __restrict__ offs, const int* __restrict__ tlist,
    float* __restrict__ out) {
  constexpr int KDIM = HID, NDIM = DIM;
  int e, mb, nb;
  if (!tile_map_g(offs, 8, (int)blockIdx.x, (int)gridDim.x, e, mb, nb)) return;
  int off = offs[e], me = offs[e + 1] - off, m0 = mb * 128, n0 = nb * 128;

  __shared__ unsigned short lds[3][2][128 * 32];

  int t = threadIdx.x, lane = t & 63, w = t >> 6;
  int wm = w >> 1, wn = w & 1;

  int kb = (lane & 3) ^ ((lane >> 3) & 3);

  const unsigned short* asrc[2];
  const unsigned short* bsrc[2];
#pragma unroll
  for (int i = 0; i < 2; i++) {
    int r = i * 64 + w * 16 + (lane >> 2);
    int gm = m0 + r;
    if (gm > me - 1) gm = me - 1;
    asrc[i] = hin + (size_t)(off + gm) * KDIM + kb * 8;
    bsrc[i] = wb + ((size_t)e * NDIM + n0 + r) * (size_t)KDIM + kb * 8;
  }

  f32x4 acc[4][4] = {};
  constexpr int NT = KDIM / 32;  // 16

  unsigned short* b0a = &lds[0][0][0]; unsigned short* b0b = &lds[0][1][0];
  unsigned short* b1a = &lds[1][0][0]; unsigned short* b1b = &lds[1][1][0];
  unsigned short* b2a = &lds[2][0][0]; unsigned short* b2b = &lds[2][1][0];

#define STAGE(kt_, da_, db_)                                       \
  do {                                                             \
    gload_lds16(asrc[0] + (kt_) * 32, (da_) + (w * 16) * 32);      \
    gload_lds16(asrc[1] + (kt_) * 32, (da_) + (64 + w * 16) * 32); \
    gload_lds16(bsrc[0] + (kt_) * 32, (db_) + (w * 16) * 32);      \
    gload_lds16(bsrc[1] + (kt_) * 32, (db_) + (64 + w * 16) * 32); \
  } while (0)

  STAGE(0, b0a, b0b);
  STAGE(1, b1a, b1b);

  for (int kt = 0; kt < NT; kt++) {
    if (kt < NT - 1) {
      asm volatile("s_waitcnt vmcnt(4)" ::: "memory");
    } else {
      asm volatile("s_waitcnt vmcnt(0)" ::: "memory");
    }
    __builtin_amdgcn_s_barrier();

    if (kt + 2 < NT) STAGE(kt + 2, b2a, b2b);

    short8 af[4], bf[4];
#pragma unroll
    for (int i = 0; i < 4; i++) {
      int ra = wm * 64 + i * 16 + (lane & 15);
      int ca = (lane >> 4) ^ ((ra >> 1) & 3);
      af[i] = *(const short8*)&b0a[ra * 32 + ca * 8];
      int rbb = wn * 64 + i * 16 + (lane & 15);
      int cb = (lane >> 4) ^ ((rbb >> 1) & 3);
      bf[i] = *(const short8*)&b0b[rbb * 32 + cb * 8];
    }
    __builtin_amdgcn_s_setprio(1);
#pragma unroll
    for (int mi = 0; mi < 4; mi++)
#pragma unroll
      for (int ni = 0; ni < 4; ni++)
        acc[mi][ni] =
            __builtin_amdgcn_mfma_f32_16x16x32_bf16(af[mi], bf[ni], acc[mi][ni], 0, 0, 0);
    __builtin_amdgcn_s_setprio(0);

    unsigned short* ta = b0a; b0a = b1a; b1a = b2a; b2a = ta;
    unsigned short* tb = b0b; b0b = b1b; b1b = b2b; b2b = tb;
  }
#undef STAGE

  int rb = (lane >> 4) * 4, cb = lane & 15;
#pragma unroll
  for (int mi = 0; mi < 4; mi++) {
#pragma unroll
    for (int j = 0; j < 4; j++) {
      int ml = wm * 64 + mi * 16 + rb + j;
      if (m0 + ml < me) {
        int tok = tlist[off + m0 + ml];
#pragma unroll
        for (int ni = 0; ni < 4; ni++) {
          int col = n0 + wn * 64 + ni * 16 + cb;
          out[(size_t)tok * DIM + col] = acc[mi][ni][j];
        }
      }
    }
  }
}

extern "C" void kernel_launch(void* const* d_in, const int* in_sizes, int n_in,
                              void* d_out, int out_size, void* d_ws, size_t ws_size,
                              hipStream_t stream) {
  const float* x = (const float*)d_in[0];
  const float* wr = (const float*)d_in[1];
  const float* wfc = (const float*)d_in[2];
  const float* wpj = (const float*)d_in[3];
  float* out = (float*)d_out;

  uintptr_t p = (uintptr_t)d_ws;
  int* offs = (int*)p;  p += 256;
  int* bc = (int*)p;    p += sizeof(int) * NB_HIST * NEXP;
  int* base = (int*)p;  p += sizeof(int) * NB_HIST * NEXP;
  int* eid = (int*)p;   p += sizeof(int) * NTOK;
  int* tlist = (int*)p; p += sizeof(int) * NTOK;
  unsigned short* wfc_b = (unsigned short*)p; p += (size_t)NEXP * HID * DIM * 2;
  unsigned short* wpj_b = (unsigned short*)p; p += (size_t)NEXP * DIM * HID * 2;
  unsigned short* hbuf = (unsigned short*)p;  p += (size_t)NTOK * HID * 2;

  k_router_cast<<<NB_ROUTER + NB_CAST, 256, 0, stream>>>(
      x, wr, eid, wfc, wpj, wfc_b, wpj_b);
  k_hist<<<NB_HIST, 256, 0, stream>>>(eid, bc);
  k_scan<<<1, 256, 0, stream>>>(bc, offs, base);
  k_scatter<<<NB_HIST, 256, 0, stream>>>(eid, base, tlist);
  // fc: 540 tiles max -> grid 544 (div by 8)
  k_gemm_fc<<<dim3(544), 256, 0, stream>>>(x, wfc_b, offs, tlist, hbuf);
  // proj: 128x128 tiles -> 1080 max (div by 8)
  k_gemm_pj<<<dim3(1080), 256, 0, stream>>>(hbuf, wpj_b, offs, tlist, out);
}

// Round 16
// 104.704 us; speedup vs baseline: 1.2989x; 1.0723x over previous
//
#include <hip/hip_runtime.h>
#include <stdint.h>
#include <stddef.h>

#define DIM 1024
#define NEXP 8
#define HID 512
#define NTOK 16384  // 4 * 4096
#define NB_HIST 64
#define NB_ROUTER 1024  // router blocks (16 tokens each)
#define NB_CAST 512     // weight-cast blocks appended after router blocks

typedef __attribute__((ext_vector_type(4))) float f32x4;
typedef __attribute__((ext_vector_type(8))) short short8;
typedef __attribute__((ext_vector_type(2))) unsigned int u32x2;
typedef __attribute__((ext_vector_type(4))) unsigned int u32x4;

__device__ __forceinline__ unsigned short f2b(float f) {
  unsigned int u = __float_as_uint(f);
  return (unsigned short)((u + 0x7FFFu + ((u >> 16) & 1u)) >> 16);  // RNE
}

// packed fp32x2 -> bf16x2 in one VALU op (RNE); round-11 win on fc (-11us).
__device__ __forceinline__ unsigned int pk_bf16(float a, float b) {
  unsigned int r;
  asm volatile("v_cvt_pk_bf16_f32 %0, %1, %2" : "=v"(r) : "v"(a), "v"(b));
  return r;
}

__device__ __forceinline__ void gload_lds16(const void* g, void* l) {
  __builtin_amdgcn_global_load_lds((const __attribute__((address_space(1))) void*)g,
                                   (__attribute__((address_space(3))) void*)l, 16, 0, 0);
}

// Router (pure read) + both weight casts (round-12 layout; r13 proved moving
// cast work between kernels is zero-sum CU-time).
__global__ __launch_bounds__(256) void k_router_cast(
    const float* __restrict__ x, const float* __restrict__ wr,
    int* __restrict__ eid,
    const float* __restrict__ wfc, const float* __restrict__ wpj,
    unsigned short* __restrict__ oa, unsigned short* __restrict__ ob) {
  int bid = blockIdx.x;
  if (bid < NB_ROUTER) {
    int w = threadIdx.x >> 6, lane = threadIdx.x & 63;
    int t0 = bid * 16 + w * 4;
    const float* xr = x + (size_t)t0 * DIM;
    float s[4][NEXP];
#pragma unroll
    for (int j = 0; j < 4; j++)
#pragma unroll
      for (int e = 0; e < NEXP; e++) s[j][e] = 0.f;
#pragma unroll
    for (int i = 0; i < 4; i++) {
      f32x4 xv[4];
#pragma unroll
      for (int j = 0; j < 4; j++) xv[j] = *(const f32x4*)(xr + j * DIM + lane * 4 + 256 * i);
#pragma unroll
      for (int e = 0; e < NEXP; e++) {
        f32x4 wv = *(const f32x4*)(wr + e * DIM + lane * 4 + 256 * i);
#pragma unroll
        for (int j = 0; j < 4; j++)
          s[j][e] += xv[j].x * wv.x + xv[j].y * wv.y + xv[j].z * wv.z + xv[j].w * wv.w;
      }
    }
#pragma unroll
    for (int j = 0; j < 4; j++)
#pragma unroll
      for (int e = 0; e < NEXP; e++) {
        float v = s[j][e];
#pragma unroll
        for (int off = 32; off > 0; off >>= 1) v += __shfl_xor(v, off);
        s[j][e] = v;
      }
    if (lane == 0) {
#pragma unroll
      for (int j = 0; j < 4; j++) {
        int be = 0;
        float bv = s[j][0];
#pragma unroll
        for (int e = 1; e < NEXP; e++) {
          if (s[j][e] > bv) { bv = s[j][e]; be = e; }
        }
        eid[t0 + j] = be;
      }
    }
  } else {
    const int n4 = NEXP * HID * DIM / 4;
    int stride = NB_CAST * 256;
    for (int i = (bid - NB_ROUTER) * 256 + (int)threadIdx.x; i < n4; i += stride) {
      f32x4 va = ((const f32x4*)wfc)[i];
      f32x4 vb = ((const f32x4*)wpj)[i];
      u32x2 ua, ub;
      ua.x = pk_bf16(va.x, va.y); ua.y = pk_bf16(va.z, va.w);
      ub.x = pk_bf16(vb.x, vb.y); ub.y = pk_bf16(vb.z, vb.w);
      ((u32x2*)oa)[i] = ua;
      ((u32x2*)ob)[i] = ub;
    }
  }
}

__global__ __launch_bounds__(256) void k_hist(const int* __restrict__ eid,
                                              int* __restrict__ bc) {
  __shared__ int h[NEXP];
  if (threadIdx.x < NEXP) h[threadIdx.x] = 0;
  __syncthreads();
  int tok = blockIdx.x * (NTOK / NB_HIST) + threadIdx.x;
  atomicAdd(&h[eid[tok]], 1);
  __syncthreads();
  if (threadIdx.x < NEXP) bc[blockIdx.x * NEXP + threadIdx.x] = h[threadIdx.x];
}

__global__ void k_scan(const int* __restrict__ bc, int* __restrict__ offs,
                       int* __restrict__ base) {
  __shared__ int cnt[NEXP];
  __shared__ int so[NEXP + 1];
  int t = threadIdx.x;
  if (t < NEXP) {
    int run = 0;
    for (int b = 0; b < NB_HIST; b++) {
      base[b * NEXP + t] = run;
      run += bc[b * NEXP + t];
    }
    cnt[t] = run;
  }
  __syncthreads();
  if (t == 0) {
    int a = 0;
    for (int e = 0; e < NEXP; e++) { so[e] = a; a += cnt[e]; }
    so[NEXP] = a;
  }
  __syncthreads();
  if (t < NEXP + 1) offs[t] = so[t];
  for (int i = t; i < NB_HIST * NEXP; i += blockDim.x) base[i] += so[i % NEXP];
}

__global__ __launch_bounds__(256) void k_scatter(const int* __restrict__ eid,
                                                 const int* __restrict__ base,
                                                 int* __restrict__ tlist) {
  __shared__ int cur[NEXP];
  if (threadIdx.x < NEXP) cur[threadIdx.x] = base[blockIdx.x * NEXP + threadIdx.x];
  __syncthreads();
  int tok = blockIdx.x * (NTOK / NB_HIST) + threadIdx.x;
  int e = eid[tok];
  int pos = atomicAdd(&cur[e], 1);
  tlist[pos] = tok;
}

// XCD-chunked mapping over G tiles (G % 8 == 0), (expert, m-block, n-block), n fastest.
__device__ __forceinline__ bool tile_map_g(const int* offs, int NB, int bid, int G,
                                           int& e, int& mb, int& nb) {
  int l = (bid & 7) * (G >> 3) + (bid >> 3);
  e = -1; mb = 0; nb = 0;
  int acc2 = 0;
#pragma unroll
  for (int i = 0; i < NEXP; i++) {
    int mi = offs[i + 1] - offs[i];
    int tb = ((mi + 127) >> 7) * NB;
    if (e < 0 && l < acc2 + tb) {
      int r = l - acc2;
      e = i; mb = r / NB; nb = r % NB;
    }
    acc2 += tb;
  }
  return e >= 0;
}

// fc GEMM — round-12 measured best (40us): A fp32 reg-staged depth-1 with
// cvt_pk conversion, B gload_lds depth-2, ring-3 48KB, steady vmcnt(2).
// r10/r14/r15 all proved deeper A-staging regresses: x is L3-resident after the
// router, so the A-wait is already covered; the residual stall is the 2-phase
// barrier skeleton itself (m233), not operand latency. Do not touch.
__global__ __launch_bounds__(256) void k_gemm_fc(
    const float* __restrict__ x, const unsigned short* __restrict__ wb,
    const int* __restrict__ offs, const int* __restrict__ tlist,
    unsigned short* __restrict__ hout) {
  constexpr int KDIM = DIM, NDIM = HID;
  int e, mb, nb;
  if (!tile_map_g(offs, 4, (int)blockIdx.x, (int)gridDim.x, e, mb, nb)) return;
  int off = offs[e], me = offs[e + 1] - off, m0 = mb * 128, n0 = nb * 128;

  __shared__ unsigned short As[3][128 * 32];
  __shared__ unsigned short Bs[3][128 * 32];

  int t = threadIdx.x, lane = t & 63, w = t >> 6;
  int wm = w >> 1, wn = w & 1;

  int kb = (lane & 3) ^ ((lane >> 3) & 3);

  const unsigned short* bsrc[2];
  const float* af32[2];
#pragma unroll
  for (int i = 0; i < 2; i++) {
    int r = i * 64 + w * 16 + (lane >> 2);
    bsrc[i] = wb + ((size_t)e * NDIM + n0 + r) * (size_t)KDIM + kb * 8;
    int gm = m0 + r;
    if (gm > me - 1) gm = me - 1;
    af32[i] = x + (size_t)tlist[off + gm] * DIM + kb * 8;
  }
  int awoff0 = (w * 16) * 32 + lane * 8;
  int awoff1 = (64 + w * 16) * 32 + lane * 8;

  f32x4 acc[4][4] = {};
  constexpr int NT = KDIM / 32;  // 32

  unsigned short* a0 = &As[0][0]; unsigned short* b0 = &Bs[0][0];
  unsigned short* a1 = &As[1][0]; unsigned short* b1 = &Bs[1][0];
  unsigned short* a2 = &As[2][0]; unsigned short* b2 = &Bs[2][0];

  f32x4 r00, r01, r10, r11;

#define ISSUE_A(kt_)                                              \
  do {                                                            \
    r00 = *(const f32x4*)(af32[0] + (kt_) * 32);                  \
    r01 = *(const f32x4*)(af32[0] + (kt_) * 32 + 4);              \
    r10 = *(const f32x4*)(af32[1] + (kt_) * 32);                  \
    r11 = *(const f32x4*)(af32[1] + (kt_) * 32 + 4);              \
  } while (0)
#define ISSUE_B(kt_, db_)                                         \
  do {                                                            \
    gload_lds16(bsrc[0] + (kt_) * 32, (db_) + (w * 16) * 32);     \
    gload_lds16(bsrc[1] + (kt_) * 32, (db_) + (64 + w * 16) * 32);\
  } while (0)
#define WRITE_A(da_)                                              \
  do {                                                            \
    u32x4 c0, c1;                                                 \
    c0.x = pk_bf16(r00.x, r00.y); c0.y = pk_bf16(r00.z, r00.w);   \
    c0.z = pk_bf16(r01.x, r01.y); c0.w = pk_bf16(r01.z, r01.w);   \
    c1.x = pk_bf16(r10.x, r10.y); c1.y = pk_bf16(r10.z, r10.w);   \
    c1.z = pk_bf16(r11.x, r11.y); c1.w = pk_bf16(r11.z, r11.w);   \
    *(u32x4*)&(da_)[awoff0] = c0;                                 \
    *(u32x4*)&(da_)[awoff1] = c1;                                 \
  } while (0)

  // prologue: A(0) x4, B(0) x2, B(1) x2 in flight
  ISSUE_A(0);
  ISSUE_B(0, b0);
  ISSUE_B(1, b1);

  for (int kt = 0; kt < NT; kt++) {
    if (kt == NT - 1) {
      asm volatile("s_waitcnt vmcnt(0)" ::: "memory");
    } else {
      asm volatile("s_waitcnt vmcnt(2)" ::: "memory");  // A(kt)+B(kt) done
    }
    __builtin_amdgcn_sched_barrier(0);
    WRITE_A(a0);
    asm volatile("s_waitcnt lgkmcnt(0)" ::: "memory");
    __builtin_amdgcn_sched_barrier(0);
    __builtin_amdgcn_s_barrier();
    if (kt + 1 < NT) ISSUE_A(kt + 1);
    if (kt + 2 < NT) ISSUE_B(kt + 2, b2);

    short8 af[4], bf[4];
#pragma unroll
    for (int i = 0; i < 4; i++) {
      int ra = wm * 64 + i * 16 + (lane & 15);
      int ca = (lane >> 4) ^ ((ra >> 1) & 3);
      af[i] = *(const short8*)&a0[ra * 32 + ca * 8];
      int rbb = wn * 64 + i * 16 + (lane & 15);
      int cb = (lane >> 4) ^ ((rbb >> 1) & 3);
      bf[i] = *(const short8*)&b0[rbb * 32 + cb * 8];
    }
    __builtin_amdgcn_s_setprio(1);
#pragma unroll
    for (int mi = 0; mi < 4; mi++)
#pragma unroll
      for (int ni = 0; ni < 4; ni++)
        acc[mi][ni] =
            __builtin_amdgcn_mfma_f32_16x16x32_bf16(af[mi], bf[ni], acc[mi][ni], 0, 0, 0);
    __builtin_amdgcn_s_setprio(0);

    unsigned short* ta = a0; a0 = a1; a1 = a2; a2 = ta;
    unsigned short* tb = b0; b0 = b1; b1 = b2; b2 = tb;
  }
#undef ISSUE_A
#undef ISSUE_B
#undef WRITE_A

  int rb = (lane >> 4) * 4, cb = lane & 15;
#pragma unroll
  for (int mi = 0; mi < 4; mi++) {
#pragma unroll
    for (int j = 0; j < 4; j++) {
      int ml = wm * 64 + mi * 16 + rb + j;
      if (m0 + ml < me) {
#pragma unroll
        for (int ni = 0; ni < 4; ni++) {
          int col = n0 + wn * 64 + ni * 16 + cb;
          float v = acc[mi][ni][j];
          v = (v >= 0.f) ? v * v : 0.25f * v * v;  // leaky(0.5) then square
          hout[(size_t)(off + m0 + ml) * HID + col] = f2b(v);
        }
      }
    }
  }
}

// proj GEMM — round-9/12 measured-best (128x128, ring-3 48KB, depth-2, vmcnt(4)).
__global__ __launch_bounds__(256) void k_gemm_pj(
    const unsigned short* __restrict__ hin, const unsigned short* __restrict__ wb,
    const int* __restrict__ offs, const int* __restrict__ tlist,
    float* __restrict__ out) {
  constexpr int KDIM = HID, NDIM = DIM;
  int e, mb, nb;
  if (!tile_map_g(offs, 8, (int)blockIdx.x, (int)gridDim.x, e, mb, nb)) return;
  int off = offs[e], me = offs[e + 1] - off, m0 = mb * 128, n0 = nb * 128;

  __shared__ unsigned short lds[3][2][128 * 32];

  int t = threadIdx.x, lane = t & 63, w = t >> 6;
  int wm = w >> 1, wn = w & 1;

  int kb = (lane & 3) ^ ((lane >> 3) & 3);

  const unsigned short* asrc[2];
  const unsigned short* bsrc[2];
#pragma unroll
  for (int i = 0; i < 2; i++) {
    int r = i * 64 + w * 16 + (lane >> 2);
    int gm = m0 + r;
    if (gm > me - 1) gm = me - 1;
    asrc[i] = hin + (size_t)(off + gm) * KDIM + kb * 8;
    bsrc[i] = wb + ((size_t)e * NDIM + n0 + r) * (size_t)KDIM + kb * 8;
  }

  f32x4 acc[4][4] = {};
  constexpr int NT = KDIM / 32;  // 16

  unsigned short* b0a = &lds[0][0][0]; unsigned short* b0b = &lds[0][1][0];
  unsigned short* b1a = &lds[1][0][0]; unsigned short* b1b = &lds[1][1][0];
  unsigned short* b2a = &lds[2][0][0]; unsigned short* b2b = &lds[2][1][0];

#define STAGE(kt_, da_, db_)                                       \
  do {                                                             \
    gload_lds16(asrc[0] + (kt_) * 32, (da_) + (w * 16) * 32);      \
    gload_lds16(asrc[1] + (kt_) * 32, (da_) + (64 + w * 16) * 32); \
    gload_lds16(bsrc[0] + (kt_) * 32, (db_) + (w * 16) * 32);      \
    gload_lds16(bsrc[1] + (kt_) * 32, (db_) + (64 + w * 16) * 32); \
  } while (0)

  STAGE(0, b0a, b0b);
  STAGE(1, b1a, b1b);

  for (int kt = 0; kt < NT; kt++) {
    if (kt < NT - 1) {
      asm volatile("s_waitcnt vmcnt(4)" ::: "memory");
    } else {
      asm volatile("s_waitcnt vmcnt(0)" ::: "memory");
    }
    __builtin_amdgcn_s_barrier();

    if (kt + 2 < NT) STAGE(kt + 2, b2a, b2b);

    short8 af[4], bf[4];
#pragma unroll
    for (int i = 0; i < 4; i++) {
      int ra = wm * 64 + i * 16 + (lane & 15);
      int ca = (lane >> 4) ^ ((ra >> 1) & 3);
      af[i] = *(const short8*)&b0a[ra * 32 + ca * 8];
      int rbb = wn * 64 + i * 16 + (lane & 15);
      int cb = (lane >> 4) ^ ((rbb >> 1) & 3);
      bf[i] = *(const short8*)&b0b[rbb * 32 + cb * 8];
    }
    __builtin_amdgcn_s_setprio(1);
#pragma unroll
    for (int mi = 0; mi < 4; mi++)
#pragma unroll
      for (int ni = 0; ni < 4; ni++)
        acc[mi][ni] =
            __builtin_amdgcn_mfma_f32_16x16x32_bf16(af[mi], bf[ni], acc[mi][ni], 0, 0, 0);
    __builtin_amdgcn_s_setprio(0);

    unsigned short* ta = b0a; b0a = b1a; b1a = b2a; b2a = ta;
    unsigned short* tb = b0b; b0b = b1b; b1b = b2b; b2b = tb;
  }
#undef STAGE

  int rb = (lane >> 4) * 4, cb = lane & 15;
#pragma unroll
  for (int mi = 0; mi < 4; mi++) {
#pragma unroll
    for (int j = 0; j < 4; j++) {
      int ml = wm * 64 + mi * 16 + rb + j;
      if (m0 + ml < me) {
        int tok = tlist[off + m0 + ml];
#pragma unroll
        for (int ni = 0; ni < 4; ni++) {
          int col = n0 + wn * 64 + ni * 16 + cb;
          out[(size_t)tok * DIM + col] = acc[mi][ni][j];
        }
      }
    }
  }
}

extern "C" void kernel_launch(void* const* d_in, const int* in_sizes, int n_in,
                              void* d_out, int out_size, void* d_ws, size_t ws_size,
                              hipStream_t stream) {
  const float* x = (const float*)d_in[0];
  const float* wr = (const float*)d_in[1];
  const float* wfc = (const float*)d_in[2];
  const float* wpj = (const float*)d_in[3];
  float* out = (float*)d_out;

  uintptr_t p = (uintptr_t)d_ws;
  int* offs = (int*)p;  p += 256;
  int* bc = (int*)p;    p += sizeof(int) * NB_HIST * NEXP;
  int* base = (int*)p;  p += sizeof(int) * NB_HIST * NEXP;
  int* eid = (int*)p;   p += sizeof(int) * NTOK;
  int* tlist = (int*)p; p += sizeof(int) * NTOK;
  unsigned short* wfc_b = (unsigned short*)p; p += (size_t)NEXP * HID * DIM * 2;
  unsigned short* wpj_b = (unsigned short*)p; p += (size_t)NEXP * DIM * HID * 2;
  unsigned short* hbuf = (unsigned short*)p;  p += (size_t)NTOK * HID * 2;

  k_router_cast<<<NB_ROUTER + NB_CAST, 256, 0, stream>>>(
      x, wr, eid, wfc, wpj, wfc_b, wpj_b);
  k_hist<<<NB_HIST, 256, 0, stream>>>(eid, bc);
  k_scan<<<1, 256, 0, stream>>>(bc, offs, base);
  k_scatter<<<NB_HIST, 256, 0, stream>>>(eid, base, tlist);
  // fc: 540 tiles max -> grid 544 (div by 8)
  k_gemm_fc<<<dim3(544), 256, 0, stream>>>(x, wfc_b, offs, tlist, hbuf);
  // proj: 128x128 tiles -> 1080 max (div by 8)
  k_gemm_pj<<<dim3(1080), 256, 0, stream>>>(hbuf, wpj_b, offs, tlist, out);
}